// Round 1
// baseline (570.798 us; speedup 1.0000x reference)
//
#include <hip/hip_runtime.h>
#include <stdint.h>

// NeighborAttention fused kernel, MI355X gfx950 — occupancy/structure round.
// B=4,N=4096,K=32,C=128,H=4,d=32. One block = 4 nodes, 256 threads (4 waves).
// Wave w owns node w of the block. Key algebra: scores = E·(q·Wk)^T, so HK is
// never materialized; HV stays in MFMA accumulators and is reduced with
// cross-quad shuffles. E is loaded global->reg A-fragments exactly once.
// LDS 17 KB, launch_bounds(256,4) -> 4 blocks/CU. Single merged kernel
// (runtime-uniform dtype branch) instead of dual template dispatch.

typedef __attribute__((ext_vector_type(8))) short short8;   // 8 bf16 = 16 B
typedef __attribute__((ext_vector_type(4))) float f32x4;

#define NPB   4
#define CDIM  128
#define KN    32
#define TSTR  136   // sT row stride in bf16 units (272 B, 16B-aligned rows)

__device__ __forceinline__ float bf2f(short s) {
    union { unsigned int u; float f; } v;
    v.u = ((unsigned int)(unsigned short)s) << 16;
    return v.f;
}
__device__ __forceinline__ short f2bf(float f) {
    union { float ff; unsigned int u; } v; v.ff = f;
    unsigned int u = v.u;
    u += 0x7FFFu + ((u >> 16) & 1u);   // round-to-nearest-even
    return (short)(u >> 16);
}

struct f8 { float v[8]; };

// load 8 consecutive logical elements starting at elem index idx, as bf16
template<bool FP32>
__device__ __forceinline__ short8 load8bf(const void* p, size_t idx) {
    if constexpr (FP32) {
        const float* fp = (const float*)p + idx;
        f32x4 a = *(const f32x4*)fp;
        f32x4 b = *(const f32x4*)(fp + 4);
        short8 r;
        r[0] = f2bf(a[0]); r[1] = f2bf(a[1]); r[2] = f2bf(a[2]); r[3] = f2bf(a[3]);
        r[4] = f2bf(b[0]); r[5] = f2bf(b[1]); r[6] = f2bf(b[2]); r[7] = f2bf(b[3]);
        return r;
    } else {
        return *(const short8*)((const short*)p + idx);
    }
}

// load 8 consecutive logical elements as fp32
template<bool FP32>
__device__ __forceinline__ f8 loadf8(const void* p, size_t idx) {
    f8 r;
    if constexpr (FP32) {
        const float* fp = (const float*)p + idx;
        f32x4 a = *(const f32x4*)fp;
        f32x4 b = *(const f32x4*)(fp + 4);
        r.v[0] = a[0]; r.v[1] = a[1]; r.v[2] = a[2]; r.v[3] = a[3];
        r.v[4] = b[0]; r.v[5] = b[1]; r.v[6] = b[2]; r.v[7] = b[3];
    } else {
        short8 s = *(const short8*)((const short*)p + idx);
        #pragma unroll
        for (int t = 0; t < 8; ++t) r.v[t] = bf2f(s[t]);
    }
    return r;
}

// load a single element as bf16
template<bool FP32>
__device__ __forceinline__ short loadbf1(const void* p, size_t idx) {
    if constexpr (FP32) return f2bf(((const float*)p)[idx]);
    else return ((const short*)p)[idx];
}

// Detect dtype of W_Q: if fp32, low half-words of floats are random bit
// patterns -> ~49% decode to |bf16|>8 (or NaN). If bf16, all |w| <= ~0.5.
__global__ void detect_dtype(const short* wq, int* flag) {
    int tid = threadIdx.x;   // 64 threads, 1 block
    int cnt = 0;
    for (int i = tid; i < 512; i += 64) {
        float v = bf2f(wq[i]);
        if (!(fabsf(v) < 8.0f)) cnt++;   // true for NaN as well
    }
    #pragma unroll
    for (int d = 1; d < 64; d <<= 1) cnt += __shfl_xor(cnt, d);
    if (tid == 0) flag[0] = (cnt > 16) ? 1 : 0;   // 1 = fp32, 0 = bf16
}

struct alignas(16) Smem {
    float sXf[NPB * CDIM];     // 2048 B   x rows (fp32)
    float sQ[NPB * CDIM];      // 2048 B   q rows (fp32)
    short sT[16 * TSTR];       // 4352 B   t = (q·Wk)*scale, bf16, [nh][j]
    float sS[512];             // 2048 B   qgemm tmp -> scores -> attn -> WO tmp
    float sCat[NPB * 384];     // 6144 B   [mean|sum|max] per node
    int   sMask[NPB * KN];     //  512 B
    float sAInv[16];           //   64 B   1/(attn_sum) per (node,h)
};                             // total ~17.2 KB

template<bool FP32>
__device__ __forceinline__ void na_body(Smem& sm,
    const void* __restrict__ hX, const void* __restrict__ hE,
    const int* __restrict__ mask, const void* __restrict__ WQ,
    const void* __restrict__ WK, const void* __restrict__ WV,
    const void* __restrict__ WO, void* __restrict__ out)
{
    const int tid  = threadIdx.x;
    const int lane = tid & 63;
    const int w    = tid >> 6;      // wave 0..3 == node within block
    const int quad = lane >> 4;
    const int l15  = lane & 15;
    const int nb   = blockIdx.x * NPB;

    // ---------------- P1: stage x rows + mask ----------------
    if (tid < 64) {
        f8 xv = loadf8<FP32>(hX, (size_t)nb * CDIM + tid * 8);
        #pragma unroll
        for (int t = 0; t < 8; ++t) sm.sXf[tid * 8 + t] = xv.v[t];
    } else if (tid < 192) {
        sm.sMask[tid - 64] = mask[(size_t)nb * KN + (tid - 64)];
    }
    __syncthreads();

    // ---------------- P2: q = x @ WQ^T (VALU; tiny) ----------------
    {
        const int c = tid & 127, half = tid >> 7;
        float a0 = 0.f, a1 = 0.f, a2 = 0.f, a3 = 0.f;
        for (int j8 = 0; j8 < 64; j8 += 8) {
            f8 wv = loadf8<FP32>(WQ, (size_t)c * CDIM + half * 64 + j8);
            const float* x0 = &sm.sXf[0 * CDIM + half * 64 + j8];
            const float* x1 = &sm.sXf[1 * CDIM + half * 64 + j8];
            const float* x2 = &sm.sXf[2 * CDIM + half * 64 + j8];
            const float* x3 = &sm.sXf[3 * CDIM + half * 64 + j8];
            #pragma unroll
            for (int t = 0; t < 8; ++t) {
                const float wf = wv.v[t];
                a0 += wf * x0[t]; a1 += wf * x1[t];
                a2 += wf * x2[t]; a3 += wf * x3[t];
            }
        }
        if (half == 1) { sm.sS[c] = a0; sm.sS[128 + c] = a1; sm.sS[256 + c] = a2; sm.sS[384 + c] = a3; }
        __syncthreads();
        if (half == 0) {
            sm.sQ[c]       = a0 + sm.sS[c];
            sm.sQ[128 + c] = a1 + sm.sS[128 + c];
            sm.sQ[256 + c] = a2 + sm.sS[256 + c];
            sm.sQ[384 + c] = a3 + sm.sS[384 + c];
        }
        __syncthreads();
    }

    // ---------------- P3: t = Qmask @ WK (scaled) via MFMA -> sT ----------------
    // t[(n,h), j] = sum_d q[n, h*32+d] * Wk[h*32+d, j]; scores = E · t^T.
    // A row (l15) = (n,h); A-frag nonzero only in k-block kk == h (exact head mask).
    {
        const int n_ = l15 >> 2, h_ = l15 & 3;
        short8 qv;
        {
            const float* qp = &sm.sQ[n_ * CDIM + h_ * 32 + quad * 8];
            #pragma unroll
            for (int t = 0; t < 8; ++t) qv[t] = f2bf(qp[t]);
        }
        const short8 zz = {0, 0, 0, 0, 0, 0, 0, 0};
        #pragma unroll
        for (int jt2 = 0; jt2 < 2; ++jt2) {
            const int j = (w * 2 + jt2) * 16 + l15;        // output col of t
            f32x4 ct4 = {0.f, 0.f, 0.f, 0.f};
            #pragma unroll
            for (int kk = 0; kk < 4; ++kk) {
                short8 bt;
                #pragma unroll
                for (int jj = 0; jj < 8; ++jj)
                    bt[jj] = loadbf1<FP32>(WK, (size_t)(kk * 32 + quad * 8 + jj) * CDIM + j);
                const short8 af = (kk == h_) ? qv : zz;
                ct4 = __builtin_amdgcn_mfma_f32_16x16x32_bf16(af, bt, ct4, 0, 0, 0);
            }
            // C layout: row = quad*4+r = (n,h), col = j. Fold in 1/sqrt(d).
            #pragma unroll
            for (int r = 0; r < 4; ++r)
                sm.sT[(quad * 4 + r) * TSTR + j] = f2bf(ct4[r] * 0.17677669529663687f);
        }
    }
    __syncthreads();

    // ---------------- P4: scores = E @ t^T via MFMA; keep E A-frags ----------------
    // Wave w loads its node's 32 e-rows (mt = 2w, 2w+1) once; frags persist for P6.
    const size_t ebase = (size_t)nb * (KN * CDIM);
    short8 aE[2][4];
    {
        short8 bs[4];
        #pragma unroll
        for (int kk = 0; kk < 4; ++kk)
            bs[kk] = *(const short8*)&sm.sT[l15 * TSTR + kk * 32 + quad * 8];
        f32x4 s0 = {0.f, 0.f, 0.f, 0.f}, s1 = {0.f, 0.f, 0.f, 0.f};
        #pragma unroll
        for (int kk = 0; kk < 4; ++kk) {
            aE[0][kk] = load8bf<FP32>(hE, ebase + (size_t)((2 * w) * 16 + l15) * CDIM + kk * 32 + quad * 8);
            aE[1][kk] = load8bf<FP32>(hE, ebase + (size_t)((2 * w + 1) * 16 + l15) * CDIM + kk * 32 + quad * 8);
            s0 = __builtin_amdgcn_mfma_f32_16x16x32_bf16(aE[0][kk], bs[kk], s0, 0, 0, 0);
            s1 = __builtin_amdgcn_mfma_f32_16x16x32_bf16(aE[1][kk], bs[kk], s1, 0, 0, 0);
        }
        // C: row = mt*16 + quad*4 + r (-> k), col = l15 = (n,h); keep n == w.
        if ((l15 >> 2) == w) {
            const int h = l15 & 3;
            #pragma unroll
            for (int r = 0; r < 4; ++r) {
                sm.sS[w * 128 + h * 32 + quad * 4 + r]      = s0[r];
                sm.sS[w * 128 + h * 32 + 16 + quad * 4 + r] = s1[r];
            }
        }
    }
    __syncthreads();

    // ---------------- P5: masked softmax (16 threads, verified code) ----------------
    if (tid < 16) {
        const int node = tid >> 2;
        const int* mp = &sm.sMask[node * 32];
        float* sp = &sm.sS[node * 128 + (tid & 3) * 32];
        float m = -3.0e38f;
        for (int k = 0; k < KN; ++k)
            m = fmaxf(m, (mp[k] > 0) ? sp[k] : -3.0e38f);
        float denom = 0.f;
        for (int k = 0; k < KN; ++k) {
            float e = __expf(fminf(sp[k] - m, 0.f)) * ((mp[k] > 0) ? 1.f : 0.f);
            sp[k] = e;
            denom += e;
        }
        const float inv = (denom > 0.f) ? (1.f / denom) : 0.f;
        for (int k = 0; k < KN; ++k)
            sp[k] = sp[k] * inv;
        const float asum = ((denom > 0.f) ? 1.0f : 0.0f) + 1e-8f;
        sm.sAInv[tid] = 1.0f / asum;
    }
    __syncthreads();

    // ---------------- P6: HV per col-tile + in-register weighted sum/max ----------------
    // av0[r] = HV[k = quad*4+r][c], av1[r] = HV[k = 16+quad*4+r][c]; reduce over k
    // = in-thread (4 r x 2 s) then shfl_xor over quads (lane^16, lane^32).
    for (int ct = 0; ct < 8; ++ct) {
        const int h = ct >> 1;
        f32x4 av0 = {0.f, 0.f, 0.f, 0.f}, av1 = {0.f, 0.f, 0.f, 0.f};
        #pragma unroll
        for (int kk = 0; kk < 4; ++kk) {
            short8 bv = load8bf<FP32>(WV, (size_t)(ct * 16 + l15) * CDIM + kk * 32 + quad * 8);
            av0 = __builtin_amdgcn_mfma_f32_16x16x32_bf16(aE[0][kk], bv, av0, 0, 0, 0);
            av1 = __builtin_amdgcn_mfma_f32_16x16x32_bf16(aE[1][kk], bv, av1, 0, 0, 0);
        }
        const float* ap = &sm.sS[w * 128 + h * 32];
        float sum = 0.f, mx = -3.0e38f;
        #pragma unroll
        for (int r = 0; r < 4; ++r) {
            const float p0 = ap[quad * 4 + r]      * av0[r];
            const float p1 = ap[16 + quad * 4 + r] * av1[r];
            sum += p0 + p1;
            mx = fmaxf(mx, fmaxf(p0, p1));
        }
        sum += __shfl_xor(sum, 16);
        sum += __shfl_xor(sum, 32);
        mx = fmaxf(mx, __shfl_xor(mx, 16));
        mx = fmaxf(mx, __shfl_xor(mx, 32));
        if (quad == 0) {
            const int c = ct * 16 + l15;
            const float inv = sm.sAInv[w * 4 + h];
            sm.sCat[w * 384 + c]       = sum * inv;   // mean
            sm.sCat[w * 384 + 128 + c] = sum;         // sum
            sm.sCat[w * 384 + 256 + c] = mx;          // max
        }
    }
    __syncthreads();

    // ---------------- P7: out = cat @ WO^T ----------------
    {
        const int c = tid & 127, half = tid >> 7;
        float acc[4] = {0.f, 0.f, 0.f, 0.f};
        for (int j8 = 0; j8 < 192; j8 += 8) {
            f8 wv = loadf8<FP32>(WO, (size_t)c * 384 + half * 192 + j8);
            #pragma unroll
            for (int t = 0; t < 8; ++t) {
                const float wf = wv.v[t];
                #pragma unroll
                for (int n = 0; n < 4; ++n)
                    acc[n] += wf * sm.sCat[n * 384 + half * 192 + j8 + t];
            }
        }
        if (half == 1) { sm.sS[c] = acc[0]; sm.sS[128 + c] = acc[1]; sm.sS[256 + c] = acc[2]; sm.sS[384 + c] = acc[3]; }
        __syncthreads();
        if (half == 0) {
            #pragma unroll
            for (int n = 0; n < 4; ++n) {
                const float val = acc[n] + sm.sS[n * 128 + c];
                if constexpr (FP32)
                    ((float*)out)[(size_t)(nb + n) * 128 + c] = val;
                else
                    ((short*)out)[(size_t)(nb + n) * 128 + c] = f2bf(val);
            }
        }
    }
}

__global__ __launch_bounds__(256, 4)
void na_fused(const void* __restrict__ hX, const void* __restrict__ hE,
              const int* __restrict__ mask, const void* __restrict__ WQ,
              const void* __restrict__ WK, const void* __restrict__ WV,
              const void* __restrict__ WO, void* __restrict__ out,
              const int* __restrict__ flag)
{
    __shared__ Smem sm;
    if (flag[0] != 0) na_body<true >(sm, hX, hE, mask, WQ, WK, WV, WO, out);
    else              na_body<false>(sm, hX, hE, mask, WQ, WK, WV, WO, out);
}

extern "C" void kernel_launch(void* const* d_in, const int* in_sizes, int n_in,
                              void* d_out, int out_size, void* d_ws, size_t ws_size,
                              hipStream_t stream) {
    (void)in_sizes; (void)n_in; (void)ws_size; (void)out_size;
    const void* hX   = d_in[0];
    const void* hE   = d_in[1];
    const int*  mask = (const int*)d_in[2];
    const void* WQ   = d_in[3];
    const void* WK   = d_in[4];
    const void* WV   = d_in[5];
    const void* WO   = d_in[6];
    int* flag = (int*)d_ws;

    detect_dtype<<<1, 64, 0, stream>>>((const short*)WQ, flag);
    na_fused<<<dim3(4096), dim3(256), 0, stream>>>(hX, hE, mask, WQ, WK, WV, WO, d_out, flag);
}

// Round 2
// 524.769 us; speedup vs baseline: 1.0877x; 1.0877x over previous
//
#include <hip/hip_runtime.h>
#include <stdint.h>

// NeighborAttention fused kernel, MI355X gfx950 — coalescing + prefetch round.
// B=4,N=4096,K=32,C=128,H=4,d=32. One block = 4 nodes, 256 threads (4 waves).
// Algebra (kept from r1): scores = E·(q·Wk)^T so HK never materialized; HV stays
// in MFMA accumulators, reduced with cross-quad shuffles.
// New (r2): E staged via coalesced cooperative loads issued at kernel TOP and
// written to LDS after the q/t gemms (latency hidden under compute); WV staged
// the same way into the dead E-tile region; WK read row-coalesced in a VALU
// t-gemm. All LDS frag patterns are 8-lanes-per-bank-group (conflict-free).

typedef __attribute__((ext_vector_type(8))) short short8;   // 8 bf16 = 16 B
typedef __attribute__((ext_vector_type(4))) float f32x4;

#define NPB   4
#define CDIM  128
#define KN    32
#define LSTR  136   // E/WV tile LDS row stride in bf16 units (272 B)
#define TSTR  136   // sT row stride

__device__ __forceinline__ float bf2f(short s) {
    union { unsigned int u; float f; } v;
    v.u = ((unsigned int)(unsigned short)s) << 16;
    return v.f;
}
__device__ __forceinline__ short f2bf(float f) {
    union { float ff; unsigned int u; } v; v.ff = f;
    unsigned int u = v.u;
    u += 0x7FFFu + ((u >> 16) & 1u);   // round-to-nearest-even
    return (short)(u >> 16);
}

struct f8 { float v[8]; };

template<bool FP32>
__device__ __forceinline__ f8 loadf8(const void* p, size_t idx) {
    f8 r;
    if constexpr (FP32) {
        const float* fp = (const float*)p + idx;
        f32x4 a = *(const f32x4*)fp;
        f32x4 b = *(const f32x4*)(fp + 4);
        r.v[0] = a[0]; r.v[1] = a[1]; r.v[2] = a[2]; r.v[3] = a[3];
        r.v[4] = b[0]; r.v[5] = b[1]; r.v[6] = b[2]; r.v[7] = b[3];
    } else {
        short8 s = *(const short8*)((const short*)p + idx);
        #pragma unroll
        for (int t = 0; t < 8; ++t) r.v[t] = bf2f(s[t]);
    }
    return r;
}

// Detect dtype of W_Q: if fp32, low half-words of floats are random bit
// patterns -> ~49% decode to |bf16|>8 (or NaN). If bf16, all |w| <= ~0.5.
__global__ void detect_dtype(const short* wq, int* flag) {
    int tid = threadIdx.x;   // 64 threads, 1 block
    int cnt = 0;
    for (int i = tid; i < 512; i += 64) {
        float v = bf2f(wq[i]);
        if (!(fabsf(v) < 8.0f)) cnt++;   // true for NaN as well
    }
    #pragma unroll
    for (int d = 1; d < 64; d <<= 1) cnt += __shfl_xor(cnt, d);
    if (tid == 0) flag[0] = (cnt > 16) ? 1 : 0;   // 1 = fp32, 0 = bf16
}

struct alignas(16) Smem {
    short sE[128 * LSTR];      // 34816 B  E tile, then WV tile (bf16)
    float sXf[NPB * CDIM];     // 2048 B   x rows (fp32)
    float sQ[NPB * CDIM];      // 2048 B   q rows (fp32)
    short sT[16 * TSTR];       // 4352 B   t = (q·Wk)*scale, bf16, [nh][ci]
    float sS[512];             // 2048 B   gemm tmp -> scores -> attn -> WO tmp
    float sCat[NPB * 384];     // 6144 B   [mean|sum|max] per node
    int   sMask[NPB * KN];     //  512 B
    float sAInv[16];           //   64 B   1/(attn_sum) per (node,h)
};                             // ~52 KB -> 3 blocks/CU

template<bool FP32>
__device__ __forceinline__ void na_body(Smem& sm,
    const void* __restrict__ hX, const void* __restrict__ hE,
    const int* __restrict__ mask, const void* __restrict__ WQ,
    const void* __restrict__ WK, const void* __restrict__ WV,
    const void* __restrict__ WO, void* __restrict__ out)
{
    const int tid  = threadIdx.x;
    const int lane = tid & 63;
    const int w    = tid >> 6;      // wave 0..3 == node within block
    const int quad = lane >> 4;
    const int l15  = lane & 15;
    const int nb   = blockIdx.x * NPB;
    const size_t ebase = (size_t)nb * (KN * CDIM);

    // ---- P0a: x rows + mask loads first (used earliest) ----
    f8 xv; int mv = 0;
    if (tid < 64) xv = loadf8<FP32>(hX, (size_t)nb * CDIM + tid * 8);
    else if (tid < 192) mv = mask[(size_t)nb * KN + (tid - 64)];

    // ---- P0b: issue coalesced E prefetch (consumed after P3) ----
    // chunk c = it*256+tid covers elements [c*8, c*8+8): 2 KB contiguous / instr.
    f32x4 eF[8][2]; short8 eB[8];
    if constexpr (FP32) {
        #pragma unroll
        for (int it = 0; it < 8; ++it) {
            const float* p = (const float*)hE + ebase + (size_t)(it * 256 + tid) * 8;
            eF[it][0] = *(const f32x4*)p;
            eF[it][1] = *(const f32x4*)(p + 4);
        }
    } else {
        #pragma unroll
        for (int it = 0; it < 8; ++it)
            eB[it] = *(const short8*)((const short*)hE + ebase + (size_t)(it * 256 + tid) * 8);
    }

    // ---- P1: stage x + mask ----
    if (tid < 64) {
        #pragma unroll
        for (int t = 0; t < 8; ++t) sm.sXf[tid * 8 + t] = xv.v[t];
    } else if (tid < 192) {
        sm.sMask[tid - 64] = mv;
    }
    __syncthreads();

    // ---- P2: q = x @ WQ^T (fp32 VALU) ----
    {
        const int c = tid & 127, half = tid >> 7;
        float a0 = 0.f, a1 = 0.f, a2 = 0.f, a3 = 0.f;
        for (int j8 = 0; j8 < 64; j8 += 8) {
            f8 wv = loadf8<FP32>(WQ, (size_t)c * CDIM + half * 64 + j8);
            const float* x0 = &sm.sXf[0 * CDIM + half * 64 + j8];
            const float* x1 = &sm.sXf[1 * CDIM + half * 64 + j8];
            const float* x2 = &sm.sXf[2 * CDIM + half * 64 + j8];
            const float* x3 = &sm.sXf[3 * CDIM + half * 64 + j8];
            #pragma unroll
            for (int t = 0; t < 8; ++t) {
                const float wf = wv.v[t];
                a0 += wf * x0[t]; a1 += wf * x1[t];
                a2 += wf * x2[t]; a3 += wf * x3[t];
            }
        }
        if (half == 1) { sm.sS[c] = a0; sm.sS[128 + c] = a1; sm.sS[256 + c] = a2; sm.sS[384 + c] = a3; }
        __syncthreads();
        if (half == 0) {
            sm.sQ[c]       = a0 + sm.sS[c];
            sm.sQ[128 + c] = a1 + sm.sS[128 + c];
            sm.sQ[256 + c] = a2 + sm.sS[256 + c];
            sm.sQ[384 + c] = a3 + sm.sS[384 + c];
        }
        __syncthreads();
    }

    // ---- P3: t[(n,h),ci] = scale * sum_d q[n,h*32+d]*WK[h*32+d][ci] ----
    // WK read ROW-coalesced: lane ci reads consecutive addresses per (h,d).
    {
        const int ci = tid & 127, half = tid >> 7;
        const int n0 = half * 2, n1 = n0 + 1;
        const float scale = 0.17677669529663687f;  // 1/sqrt(32)
        #pragma unroll
        for (int h = 0; h < 4; ++h) {
            float a0 = 0.f, a1 = 0.f;
            #pragma unroll
            for (int d = 0; d < 32; ++d) {
                float wk;
                if constexpr (FP32) wk = ((const float*)WK)[(size_t)(h * 32 + d) * CDIM + ci];
                else                wk = bf2f(((const short*)WK)[(size_t)(h * 32 + d) * CDIM + ci]);
                a0 += sm.sQ[n0 * CDIM + h * 32 + d] * wk;
                a1 += sm.sQ[n1 * CDIM + h * 32 + d] * wk;
            }
            sm.sT[(n0 * 4 + h) * TSTR + ci] = f2bf(a0 * scale);
            sm.sT[(n1 * 4 + h) * TSTR + ci] = f2bf(a1 * scale);
        }
    }

    // ---- E convert + coalesced LDS write (E loads now long complete) ----
    #pragma unroll
    for (int it = 0; it < 8; ++it) {
        const int chunk = it * 256 + tid, row = chunk >> 4, cc = chunk & 15;
        short8 v;
        if constexpr (FP32) {
            #pragma unroll
            for (int t = 0; t < 4; ++t) { v[t] = f2bf(eF[it][0][t]); v[4 + t] = f2bf(eF[it][1][t]); }
        } else v = eB[it];
        *(short8*)&sm.sE[row * LSTR + cc * 8] = v;
    }

    // ---- issue WV prefetch (consumed in P5 region, hidden under P4) ----
    f32x4 vF[8][2]; short8 vB[8];
    if constexpr (FP32) {
        #pragma unroll
        for (int it = 0; it < 8; ++it) {
            const float* p = (const float*)WV + (size_t)(it * 256 + tid) * 8;
            vF[it][0] = *(const f32x4*)p;
            vF[it][1] = *(const f32x4*)(p + 4);
        }
    } else {
        #pragma unroll
        for (int it = 0; it < 8; ++it)
            vB[it] = *(const short8*)((const short*)WV + (size_t)(it * 256 + tid) * 8);
    }
    __syncthreads();   // sT + sE ready

    // ---- P4: scores = E @ t^T via MFMA; keep E A-frags in regs ----
    short8 aE[2][4];
    {
        short8 bs[4];
        #pragma unroll
        for (int kk = 0; kk < 4; ++kk)
            bs[kk] = *(const short8*)&sm.sT[l15 * TSTR + kk * 32 + quad * 8];
        #pragma unroll
        for (int s = 0; s < 2; ++s)
            #pragma unroll
            for (int kk = 0; kk < 4; ++kk)
                aE[s][kk] = *(const short8*)&sm.sE[((2 * w + s) * 16 + l15) * LSTR + kk * 32 + quad * 8];
        f32x4 s0 = {0.f, 0.f, 0.f, 0.f}, s1 = {0.f, 0.f, 0.f, 0.f};
        #pragma unroll
        for (int kk = 0; kk < 4; ++kk) {
            s0 = __builtin_amdgcn_mfma_f32_16x16x32_bf16(aE[0][kk], bs[kk], s0, 0, 0, 0);
            s1 = __builtin_amdgcn_mfma_f32_16x16x32_bf16(aE[1][kk], bs[kk], s1, 0, 0, 0);
        }
        // C: row = mt*16 + quad*4 + r (-> k), col = l15 = (n,h); keep n == w.
        if ((l15 >> 2) == w) {
            const int h = l15 & 3;
            #pragma unroll
            for (int r = 0; r < 4; ++r) {
                sm.sS[w * 128 + h * 32 + quad * 4 + r]      = s0[r];
                sm.sS[w * 128 + h * 32 + 16 + quad * 4 + r] = s1[r];
            }
        }
    }
    __syncthreads();   // all sE frag reads + score writes done

    // ---- P5: masked softmax (16 threads) + WV convert/write by all ----
    if (tid < 16) {
        const int node = tid >> 2;
        const int* mp = &sm.sMask[node * 32];
        float* sp = &sm.sS[node * 128 + (tid & 3) * 32];
        float m = -3.0e38f;
        for (int k = 0; k < KN; ++k)
            m = fmaxf(m, (mp[k] > 0) ? sp[k] : -3.0e38f);
        float denom = 0.f;
        for (int k = 0; k < KN; ++k) {
            float e = __expf(fminf(sp[k] - m, 0.f)) * ((mp[k] > 0) ? 1.f : 0.f);
            sp[k] = e;
            denom += e;
        }
        const float inv = (denom > 0.f) ? (1.f / denom) : 0.f;
        for (int k = 0; k < KN; ++k)
            sp[k] = sp[k] * inv;
        const float asum = ((denom > 0.f) ? 1.0f : 0.0f) + 1e-8f;
        sm.sAInv[tid] = 1.0f / asum;
    }
    #pragma unroll
    for (int it = 0; it < 8; ++it) {
        const int chunk = it * 256 + tid, row = chunk >> 4, cc = chunk & 15;
        short8 v;
        if constexpr (FP32) {
            #pragma unroll
            for (int t = 0; t < 4; ++t) { v[t] = f2bf(vF[it][0][t]); v[4 + t] = f2bf(vF[it][1][t]); }
        } else v = vB[it];
        *(short8*)&sm.sE[row * LSTR + cc * 8] = v;   // WV tile [c][ci]
    }
    __syncthreads();   // attn + WV tile ready

    // ---- P6: HV per col-tile + in-register weighted sum/max ----
    for (int ct = 0; ct < 8; ++ct) {
        const int h = ct >> 1;
        f32x4 av0 = {0.f, 0.f, 0.f, 0.f}, av1 = {0.f, 0.f, 0.f, 0.f};
        #pragma unroll
        for (int kk = 0; kk < 4; ++kk) {
            short8 bv = *(const short8*)&sm.sE[(ct * 16 + l15) * LSTR + kk * 32 + quad * 8];
            av0 = __builtin_amdgcn_mfma_f32_16x16x32_bf16(aE[0][kk], bv, av0, 0, 0, 0);
            av1 = __builtin_amdgcn_mfma_f32_16x16x32_bf16(aE[1][kk], bv, av1, 0, 0, 0);
        }
        const float* ap = &sm.sS[w * 128 + h * 32];
        float sum = 0.f, mx = -3.0e38f;
        #pragma unroll
        for (int r = 0; r < 4; ++r) {
            const float p0 = ap[quad * 4 + r]      * av0[r];
            const float p1 = ap[16 + quad * 4 + r] * av1[r];
            sum += p0 + p1;
            mx = fmaxf(mx, fmaxf(p0, p1));
        }
        sum += __shfl_xor(sum, 16);
        sum += __shfl_xor(sum, 32);
        mx = fmaxf(mx, __shfl_xor(mx, 16));
        mx = fmaxf(mx, __shfl_xor(mx, 32));
        if (quad == 0) {
            const int c = ct * 16 + l15;
            const float inv = sm.sAInv[w * 4 + h];
            sm.sCat[w * 384 + c]       = sum * inv;   // mean
            sm.sCat[w * 384 + 128 + c] = sum;         // sum
            sm.sCat[w * 384 + 256 + c] = mx;          // max
        }
    }
    __syncthreads();

    // ---- P7: out = cat @ WO^T (fp32 VALU) ----
    {
        const int c = tid & 127, half = tid >> 7;
        float acc[4] = {0.f, 0.f, 0.f, 0.f};
        for (int j8 = 0; j8 < 192; j8 += 8) {
            f8 wv = loadf8<FP32>(WO, (size_t)c * 384 + half * 192 + j8);
            #pragma unroll
            for (int t = 0; t < 8; ++t) {
                const float wf = wv.v[t];
                #pragma unroll
                for (int n = 0; n < 4; ++n)
                    acc[n] += wf * sm.sCat[n * 384 + half * 192 + j8 + t];
            }
        }
        if (half == 1) { sm.sS[c] = acc[0]; sm.sS[128 + c] = acc[1]; sm.sS[256 + c] = acc[2]; sm.sS[384 + c] = acc[3]; }
        __syncthreads();
        if (half == 0) {
            #pragma unroll
            for (int n = 0; n < 4; ++n) {
                const float val = acc[n] + sm.sS[n * 128 + c];
                if constexpr (FP32)
                    ((float*)out)[(size_t)(nb + n) * 128 + c] = val;
                else
                    ((short*)out)[(size_t)(nb + n) * 128 + c] = f2bf(val);
            }
        }
    }
}

__global__ __launch_bounds__(256, 3)
void na_fused(const void* __restrict__ hX, const void* __restrict__ hE,
              const int* __restrict__ mask, const void* __restrict__ WQ,
              const void* __restrict__ WK, const void* __restrict__ WV,
              const void* __restrict__ WO, void* __restrict__ out,
              const int* __restrict__ flag)
{
    __shared__ Smem sm;
    if (flag[0] != 0) na_body<true >(sm, hX, hE, mask, WQ, WK, WV, WO, out);
    else              na_body<false>(sm, hX, hE, mask, WQ, WK, WV, WO, out);
}

extern "C" void kernel_launch(void* const* d_in, const int* in_sizes, int n_in,
                              void* d_out, int out_size, void* d_ws, size_t ws_size,
                              hipStream_t stream) {
    (void)in_sizes; (void)n_in; (void)ws_size; (void)out_size;
    const void* hX   = d_in[0];
    const void* hE   = d_in[1];
    const int*  mask = (const int*)d_in[2];
    const void* WQ   = d_in[3];
    const void* WK   = d_in[4];
    const void* WV   = d_in[5];
    const void* WO   = d_in[6];
    int* flag = (int*)d_ws;

    detect_dtype<<<1, 64, 0, stream>>>((const short*)WQ, flag);
    na_fused<<<dim3(4096), dim3(256), 0, stream>>>(hX, hE, mask, WQ, WK, WV, WO, d_out, flag);
}

// Round 3
// 401.612 us; speedup vs baseline: 1.4213x; 1.3067x over previous
//
#include <hip/hip_runtime.h>
#include <stdint.h>

// NeighborAttention fused kernel, MI355X gfx950 — round 3: big-tile + all-MFMA.
// B=4,N=4096,K=32,C=128,H=4,d=32. One block = 16 nodes, 256 threads (4 waves),
// grid = 1024. E streamed in 4 subtiles (128x128) with 1-deep reg prefetch.
// All gemms on the matrix pipe: q = X·WQ^T (MFMA), t = q·WK (masked-head MFMA,
// so HK is never materialized), scores = E·t^T, HV = E·WV^T (accum in regs,
// cross-quad shuffle aggregation), out = cat·WO^T (MFMA). Weights held as
// register fragments for the whole block. Wave-parallel masked softmax.
// LDS 73.5 KB -> 2 blocks/CU. dtype (fp32 vs bf16) detected in-kernel.

typedef __attribute__((ext_vector_type(8))) short short8;   // 8 bf16 = 16 B
typedef __attribute__((ext_vector_type(4))) float f32x4;

#define NPB   16
#define CDIM  128
#define KN    32
#define ESTR  136   // sE row stride (bf16 units)
#define TSTR  136   // sT row stride
#define QSTR  136   // sQ row stride
#define CATS  392   // sCat row stride (bf16 units), 384 data + pad
#define SSTR  36    // sS row stride (fp32 units), 32 data + pad

__device__ __forceinline__ float bf2f(short s) {
    union { unsigned int u; float f; } v;
    v.u = ((unsigned int)(unsigned short)s) << 16;
    return v.f;
}
__device__ __forceinline__ short f2bf(float f) {
    union { float ff; unsigned int u; } v; v.ff = f;
    unsigned int u = v.u;
    u += 0x7FFFu + ((u >> 16) & 1u);   // round-to-nearest-even
    return (short)(u >> 16);
}

struct f8 { float v[8]; };

template<bool FP32>
__device__ __forceinline__ short8 load8bf(const void* p, size_t idx) {
    if constexpr (FP32) {
        const float* fp = (const float*)p + idx;
        f32x4 a = *(const f32x4*)fp;
        f32x4 b = *(const f32x4*)(fp + 4);
        short8 r;
        r[0] = f2bf(a[0]); r[1] = f2bf(a[1]); r[2] = f2bf(a[2]); r[3] = f2bf(a[3]);
        r[4] = f2bf(b[0]); r[5] = f2bf(b[1]); r[6] = f2bf(b[2]); r[7] = f2bf(b[3]);
        return r;
    } else {
        return *(const short8*)((const short*)p + idx);
    }
}

template<bool FP32>
__device__ __forceinline__ short loadbf1(const void* p, size_t idx) {
    if constexpr (FP32) return f2bf(((const float*)p)[idx]);
    else return ((const short*)p)[idx];
}

struct alignas(16) Smem {
    short sE[128 * ESTR];     // 34816 B  E subtile (bf16)
    short sT[64 * TSTR];      // 17408 B  t = (q·Wk)*scale (bf16) [nh][ci]
    short sQ[16 * QSTR];      //  4352 B  q rows (bf16)
    short sCat[16 * CATS];    // 12544 B  [mean|sum|max] per node (bf16)
    float sS[16 * SSTR];      //  2304 B  scores -> attn, per subtile [nh][k]
    int   sMask[NPB * KN];    //  2048 B
    float sAInv[16];          //    64 B  per-subtile 1/(attn_sum+eps)
};                            // 73536 B -> 2 blocks/CU

template<bool FP32>
__device__ __forceinline__ void issueE(const void* hE, size_t base, int tid,
                                       f32x4 (&eF)[8][2], short8 (&eB)[8]) {
    if constexpr (FP32) {
        #pragma unroll
        for (int it = 0; it < 8; ++it) {
            const float* p = (const float*)hE + base + (size_t)(it * 256 + tid) * 8;
            eF[it][0] = *(const f32x4*)p;
            eF[it][1] = *(const f32x4*)(p + 4);
        }
    } else {
        #pragma unroll
        for (int it = 0; it < 8; ++it)
            eB[it] = *(const short8*)((const short*)hE + base + (size_t)(it * 256 + tid) * 8);
    }
}

template<bool FP32>
__device__ __forceinline__ void writeE(short* sE, int tid,
                                       const f32x4 (&eF)[8][2], const short8 (&eB)[8]) {
    #pragma unroll
    for (int it = 0; it < 8; ++it) {
        const int chunk = it * 256 + tid, row = chunk >> 4, cc = chunk & 15;
        short8 v;
        if constexpr (FP32) {
            #pragma unroll
            for (int t = 0; t < 4; ++t) { v[t] = f2bf(eF[it][0][t]); v[4 + t] = f2bf(eF[it][1][t]); }
        } else v = eB[it];
        *(short8*)&sE[row * ESTR + cc * 8] = v;
    }
}

template<bool FP32>
__device__ __forceinline__ void na_body(Smem& sm,
    const void* __restrict__ hX, const void* __restrict__ hE,
    const int* __restrict__ mask, const void* __restrict__ WQ,
    const void* __restrict__ WK, const void* __restrict__ WV,
    const void* __restrict__ WO, void* __restrict__ out)
{
    const int tid  = threadIdx.x;
    const int lane = tid & 63;
    const int w    = tid >> 6;      // wave 0..3
    const int quad = lane >> 4;
    const int l15  = lane & 15;
    const int nb   = blockIdx.x * NPB;
    const size_t ebase = (size_t)nb * (KN * CDIM);

    // ---- stage mask (coalesced, 2 ints/thread) ----
    *(int2*)&sm.sMask[tid * 2] = *(const int2*)&mask[(size_t)nb * KN + tid * 2];

    // ---- issue E subtile-0 prefetch ----
    f32x4 eF[8][2]; short8 eB[8];
    issueE<FP32>(hE, ebase, tid, eF, eB);

    // ---- X A-frags: row l15 = node, elems kk*32+quad*8.. ----
    short8 ax[4];
    #pragma unroll
    for (int kk = 0; kk < 4; ++kk)
        ax[kk] = load8bf<FP32>(hX, (size_t)(nb + l15) * CDIM + kk * 32 + quad * 8);

    // ---- WQ B-frags: col c = w*32+t2*16+l15, B[c-dim elems] = WQ[o][c]... (o=col) ----
    short8 bq[2][4];
    #pragma unroll
    for (int t2 = 0; t2 < 2; ++t2)
        #pragma unroll
        for (int kk = 0; kk < 4; ++kk)
            bq[t2][kk] = load8bf<FP32>(WQ, (size_t)(w * 32 + t2 * 16 + l15) * CDIM + kk * 32 + quad * 8);

    // ---- WV B-frags (block-lifetime): wave w owns cols [32w,32w+32) ----
    short8 bv[2][4];
    #pragma unroll
    for (int ct = 0; ct < 2; ++ct)
        #pragma unroll
        for (int kk = 0; kk < 4; ++kk)
            bv[ct][kk] = load8bf<FP32>(WV, (size_t)((2 * w + ct) * 16 + l15) * CDIM + kk * 32 + quad * 8);

    // ---- WK B-frags for t-gemm: B[k_red][j] = WK[k_red][j] (scalar gather, once) ----
    short8 bk[2][4];
    #pragma unroll
    for (int t2 = 0; t2 < 2; ++t2)
        #pragma unroll
        for (int kk = 0; kk < 4; ++kk) {
            const int j = w * 32 + t2 * 16 + l15;
            short8 b;
            #pragma unroll
            for (int jj = 0; jj < 8; ++jj)
                b[jj] = loadbf1<FP32>(WK, (size_t)(kk * 32 + quad * 8 + jj) * CDIM + j);
            bk[t2][kk] = b;
        }

    // ---- q = X @ WQ^T via MFMA -> sQ (bf16) ----
    {
        f32x4 o0 = {0.f,0.f,0.f,0.f}, o1 = {0.f,0.f,0.f,0.f};
        #pragma unroll
        for (int kk = 0; kk < 4; ++kk) {
            o0 = __builtin_amdgcn_mfma_f32_16x16x32_bf16(ax[kk], bq[0][kk], o0, 0, 0, 0);
            o1 = __builtin_amdgcn_mfma_f32_16x16x32_bf16(ax[kk], bq[1][kk], o1, 0, 0, 0);
        }
        #pragma unroll
        for (int r = 0; r < 4; ++r) {
            const int n = quad * 4 + r;                       // C row = node
            sm.sQ[n * QSTR + w * 32 + l15]      = f2bf(o0[r]);
            sm.sQ[n * QSTR + w * 32 + 16 + l15] = f2bf(o1[r]);
        }
    }
    __syncthreads();   // B1: sQ + sMask ready

    // ---- t = (q · WK)*scale via masked-head MFMA -> sT (bf16) ----
    {
        const float scale = 0.17677669529663687f;   // 1/sqrt(32)
        const short8 zz = {0,0,0,0,0,0,0,0};
        #pragma unroll
        for (int m = 0; m < 4; ++m) {
            const int n_g = m * 4 + (l15 >> 2), h_ = l15 & 3;
            const short8 qv = *(const short8*)&sm.sQ[n_g * QSTR + h_ * 32 + quad * 8];
            f32x4 c0 = {0.f,0.f,0.f,0.f}, c1 = {0.f,0.f,0.f,0.f};
            #pragma unroll
            for (int kk = 0; kk < 4; ++kk) {
                const short8 af = (kk == h_) ? qv : zz;
                c0 = __builtin_amdgcn_mfma_f32_16x16x32_bf16(af, bk[0][kk], c0, 0, 0, 0);
                c1 = __builtin_amdgcn_mfma_f32_16x16x32_bf16(af, bk[1][kk], c1, 0, 0, 0);
            }
            #pragma unroll
            for (int r = 0; r < 4; ++r) {
                const int row = m * 16 + quad * 4 + r;        // (n,h) row
                sm.sT[row * TSTR + w * 32 + l15]      = f2bf(c0[r] * scale);
                sm.sT[row * TSTR + w * 32 + 16 + l15] = f2bf(c1[r] * scale);
            }
        }
    }

    // ---- write E0 to sE; issue E1 ----
    writeE<FP32>(sm.sE, tid, eF, eB);
    issueE<FP32>(hE, ebase + 1 * 128 * 128, tid, eF, eB);
    __syncthreads();   // B2: sT + sE(0) ready

    // ================= subtile loop (4 nodes each) =================
    #pragma unroll 1
    for (int s = 0; s < 4; ++s) {
        // ---- P4: scores = E_sub @ t_sub^T (wave = node_local) ----
        {
            short8 bs[4], a0[4], a1[4];
            #pragma unroll
            for (int kk = 0; kk < 4; ++kk) {
                bs[kk] = *(const short8*)&sm.sT[(16 * s + l15) * TSTR + kk * 32 + quad * 8];
                a0[kk] = *(const short8*)&sm.sE[(w * 32 + l15) * ESTR + kk * 32 + quad * 8];
                a1[kk] = *(const short8*)&sm.sE[(w * 32 + 16 + l15) * ESTR + kk * 32 + quad * 8];
            }
            f32x4 s0 = {0.f,0.f,0.f,0.f}, s1 = {0.f,0.f,0.f,0.f};
            #pragma unroll
            for (int kk = 0; kk < 4; ++kk) {
                s0 = __builtin_amdgcn_mfma_f32_16x16x32_bf16(a0[kk], bs[kk], s0, 0, 0, 0);
                s1 = __builtin_amdgcn_mfma_f32_16x16x32_bf16(a1[kk], bs[kk], s1, 0, 0, 0);
            }
            if ((l15 >> 2) == w) {       // keep cols of own node
                const int h = l15 & 3;
                #pragma unroll
                for (int r = 0; r < 4; ++r) {
                    sm.sS[(w * 4 + h) * SSTR + quad * 4 + r]      = s0[r];
                    sm.sS[(w * 4 + h) * SSTR + 16 + quad * 4 + r] = s1[r];
                }
            }
        }
        __syncthreads();

        // ---- P5: masked softmax, wave-parallel (wave 0: 4 lanes per (n,h)) ----
        if (tid < 64) {
            const int nh = lane >> 2, sub = lane & 3, n_ = nh >> 2;
            const int* mp = &sm.sMask[(s * 4 + n_) * KN];
            float* sp = &sm.sS[nh * SSTR];
            float x[8]; int mk[8];
            #pragma unroll
            for (int j = 0; j < 8; ++j) { const int k = sub * 8 + j; mk[j] = mp[k]; x[j] = sp[k]; }
            float m = -3.0e38f;
            #pragma unroll
            for (int j = 0; j < 8; ++j) m = fmaxf(m, (mk[j] > 0) ? x[j] : -3.0e38f);
            m = fmaxf(m, __shfl_xor(m, 1));
            m = fmaxf(m, __shfl_xor(m, 2));
            float dsum = 0.f;
            #pragma unroll
            for (int j = 0; j < 8; ++j) {
                const float e = __expf(fminf(x[j] - m, 0.f)) * ((mk[j] > 0) ? 1.f : 0.f);
                x[j] = e; dsum += e;
            }
            dsum += __shfl_xor(dsum, 1);
            dsum += __shfl_xor(dsum, 2);
            const float inv = (dsum > 0.f) ? (1.f / dsum) : 0.f;
            #pragma unroll
            for (int j = 0; j < 8; ++j) sp[sub * 8 + j] = x[j] * inv;
            if (sub == 0) sm.sAInv[nh] = 1.0f / (((dsum > 0.f) ? 1.0f : 0.0f) + 1e-8f);
        }
        __syncthreads();

        // ---- P6: HV + weighted sum/mean/max (wave = ct-pair, head h == w) ----
        #pragma unroll
        for (int n_ = 0; n_ < 4; ++n_) {
            short8 a0[4], a1[4];
            #pragma unroll
            for (int kk = 0; kk < 4; ++kk) {
                a0[kk] = *(const short8*)&sm.sE[(n_ * 32 + l15) * ESTR + kk * 32 + quad * 8];
                a1[kk] = *(const short8*)&sm.sE[(n_ * 32 + 16 + l15) * ESTR + kk * 32 + quad * 8];
            }
            const float* ap = &sm.sS[(n_ * 4 + w) * SSTR];
            const float inv = sm.sAInv[n_ * 4 + w];
            #pragma unroll
            for (int ct = 0; ct < 2; ++ct) {
                f32x4 av0 = {0.f,0.f,0.f,0.f}, av1 = {0.f,0.f,0.f,0.f};
                #pragma unroll
                for (int kk = 0; kk < 4; ++kk) {
                    av0 = __builtin_amdgcn_mfma_f32_16x16x32_bf16(a0[kk], bv[ct][kk], av0, 0, 0, 0);
                    av1 = __builtin_amdgcn_mfma_f32_16x16x32_bf16(a1[kk], bv[ct][kk], av1, 0, 0, 0);
                }
                float sum = 0.f, mx = -3.0e38f;
                #pragma unroll
                for (int r = 0; r < 4; ++r) {
                    const float p0 = ap[quad * 4 + r]      * av0[r];
                    const float p1 = ap[16 + quad * 4 + r] * av1[r];
                    sum += p0 + p1;
                    mx = fmaxf(mx, fmaxf(p0, p1));
                }
                sum += __shfl_xor(sum, 16);
                sum += __shfl_xor(sum, 32);
                mx = fmaxf(mx, __shfl_xor(mx, 16));
                mx = fmaxf(mx, __shfl_xor(mx, 32));
                if (quad == 0) {
                    const int c = (2 * w + ct) * 16 + l15, row = s * 4 + n_;
                    sm.sCat[row * CATS + c]       = f2bf(sum * inv);   // mean
                    sm.sCat[row * CATS + 128 + c] = f2bf(sum);         // sum
                    sm.sCat[row * CATS + 256 + c] = f2bf(mx);          // max
                }
            }
        }
        __syncthreads();   // sE reads done; sCat rows of subtile s written

        if (s < 3) {
            writeE<FP32>(sm.sE, tid, eF, eB);                         // sE = E[s+1]
            if (s < 2) issueE<FP32>(hE, ebase + (size_t)(s + 2) * 128 * 128, tid, eF, eB);
            __syncthreads();   // sE ready
        }
    }

    // ---- P7: out = cat @ WO^T via MFMA (M=16, K=384, wave owns 32 cols) ----
    {
        f32x4 o0 = {0.f,0.f,0.f,0.f}, o1 = {0.f,0.f,0.f,0.f};
        #pragma unroll
        for (int kk = 0; kk < 12; ++kk) {
            const short8 a  = *(const short8*)&sm.sCat[l15 * CATS + kk * 32 + quad * 8];
            const short8 b0 = load8bf<FP32>(WO, (size_t)(w * 32 + l15) * 384 + kk * 32 + quad * 8);
            const short8 b1 = load8bf<FP32>(WO, (size_t)(w * 32 + 16 + l15) * 384 + kk * 32 + quad * 8);
            o0 = __builtin_amdgcn_mfma_f32_16x16x32_bf16(a, b0, o0, 0, 0, 0);
            o1 = __builtin_amdgcn_mfma_f32_16x16x32_bf16(a, b1, o1, 0, 0, 0);
        }
        #pragma unroll
        for (int r = 0; r < 4; ++r) {
            const int node = quad * 4 + r;
            const size_t base = (size_t)(nb + node) * CDIM + w * 32;
            if constexpr (FP32) {
                ((float*)out)[base + l15]      = o0[r];
                ((float*)out)[base + 16 + l15] = o1[r];
            } else {
                ((short*)out)[base + l15]      = f2bf(o0[r]);
                ((short*)out)[base + 16 + l15] = f2bf(o1[r]);
            }
        }
    }
}

__global__ __launch_bounds__(256, 2)
void na_fused(const void* __restrict__ hX, const void* __restrict__ hE,
              const int* __restrict__ mask, const void* __restrict__ WQ,
              const void* __restrict__ WK, const void* __restrict__ WV,
              const void* __restrict__ WO, void* __restrict__ out)
{
    __shared__ Smem sm;
    // in-kernel dtype detect on WQ[0..511]: fp32 low halves decode to wild bf16s
    const short* wq16 = (const short*)WQ;
    const int lane = threadIdx.x & 63;
    int cnt = 0;
    #pragma unroll
    for (int i = 0; i < 8; ++i) {
        const float v = bf2f(wq16[lane + i * 64]);
        if (!(fabsf(v) < 8.0f)) cnt++;
    }
    #pragma unroll
    for (int d = 1; d < 64; d <<= 1) cnt += __shfl_xor(cnt, d);
    if (cnt > 16) na_body<true >(sm, hX, hE, mask, WQ, WK, WV, WO, out);
    else          na_body<false>(sm, hX, hE, mask, WQ, WK, WV, WO, out);
}

extern "C" void kernel_launch(void* const* d_in, const int* in_sizes, int n_in,
                              void* d_out, int out_size, void* d_ws, size_t ws_size,
                              hipStream_t stream) {
    (void)in_sizes; (void)n_in; (void)ws_size; (void)out_size; (void)d_ws;
    const void* hX   = d_in[0];
    const void* hE   = d_in[1];
    const int*  mask = (const int*)d_in[2];
    const void* WQ   = d_in[3];
    const void* WK   = d_in[4];
    const void* WV   = d_in[5];
    const void* WO   = d_in[6];

    na_fused<<<dim3(1024), dim3(256), 0, stream>>>(hX, hE, mask, WQ, WK, WV, WO, d_out);
}